// Round 10
// baseline (105.814 us; speedup 1.0000x reference)
//
#include <hip/hip_runtime.h>
#include <math.h>

// Hungarian matcher cost matrix:
//   C[n,t] = 5*L1(xyxy) + 2*(focal@label[t]) - 2*GIoU + 9999*inner
// N = 14400, T = 1024, C = 91. Output [N,T] f32 (59 MB).
//
// R10: every fused variant (R2-R4,R8,R9) is pinned at ~43us regardless of
// VALU/LDS/store-policy changes; only the fill kernels (6 TB/s) differ in
// SHAPE: tiny per-thread work, enormous block count. Restructure to match:
//   - grid = N = 14400 blocks (one row per block), 256 thr x VT=4 cols
//   - ONE float4 store per thread, no serial row loop
//   - row constants: block-uniform packed [n][8] -> scalar s_load
//   - target constants: SoA arrays -> perfectly coalesced dwordx4 loads
//   - class cost: prep-built row-major table[n][96], 4 gathers in a 384B
//     block-uniform span (L2-hit, each row read exactly once)
// Prep: linear-index table kernel + pack kernel (both coalesced, ~4us).

#define TSTR 96

// ws layout (bytes): table @ 0 : N*96*4 = 5,529,600
#define TGT_OFF  0x550000   // 6 SoA arrays x 4KB (tx0,ty0,tx1,ty1,tarea,lab)
#define ROW_OFF  0x560000   // rowpack [N][8] floats = 460,800 B
// total <= 0x5D0800 = 6.1 MB (ws was >= this in R7, passed)

__global__ __launch_bounds__(256) void prep_table(
    const float* __restrict__ logits,   // [N, C]
    const float* __restrict__ objs,     // [N, 1]
    float* __restrict__ ws,
    int N, int C)
{
    int idx = blockIdx.x * 256 + threadIdx.x;   // linear over N*C
    if (idx >= N * C) return;
    int n = idx / C;
    int c = idx - n * C;
    float po = __builtin_amdgcn_rcpf(1.0f + __expf(-objs[n]));
    float lg = logits[idx];                      // coalesced
    float ps = __builtin_amdgcn_rcpf(1.0f + __expf(-lg));
    float p = ps * po;
    float omp = 1.0f - p;
    float pos = 0.25f * (omp * omp) * (-__logf(p + 1e-8f));
    float neg = 0.75f * (p * p) * (-__logf(omp + 1e-8f));
    ws[(size_t)n * TSTR + c] = pos - neg;        // coalesced (96-stride rows)
}

__global__ __launch_bounds__(256) void prep_packs(
    const float* __restrict__ boxes,    // [N, 4] cxcywh
    const float* __restrict__ points,   // [N, 2]
    const int*   __restrict__ labels,   // [T]
    const float* __restrict__ tboxes,   // [T, 4] cxcywh
    float* __restrict__ ws,
    int N, int T)
{
    int i = blockIdx.x * 256 + threadIdx.x;
    float* rowpack = (float*)((char*)ws + ROW_OFF);
    if (i < N) {
        float4 b = *(const float4*)(boxes + 4 * i);
        float x0 = b.x - 0.5f * b.z;
        float y0 = b.y - 0.5f * b.w;
        float x1 = b.x + 0.5f * b.z;
        float y1 = b.y + 0.5f * b.w;
        float2 p = *(const float2*)(points + 2 * i);
        float* rp = rowpack + 8 * i;
        rp[0] = x0; rp[1] = y0; rp[2] = x1; rp[3] = y1;
        rp[4] = p.x; rp[5] = p.y; rp[6] = (x1 - x0) * (y1 - y0); rp[7] = 0.f;
    }
    if (i < T) {
        float* tgt = (float*)((char*)ws + TGT_OFF);
        float* tx0 = tgt;            float* ty0 = tgt + 1024;
        float* tx1 = tgt + 2048;     float* ty1 = tgt + 3072;
        float* tar = tgt + 4096;     int*   tlb = (int*)(tgt + 5120);
        float4 tb = *(const float4*)(tboxes + 4 * i);
        float x0 = tb.x - 0.5f * tb.z;
        float y0 = tb.y - 0.5f * tb.w;
        float x1 = tb.x + 0.5f * tb.z;
        float y1 = tb.y + 0.5f * tb.w;
        tx0[i] = x0; ty0[i] = y0; tx1[i] = x1; ty1[i] = y1;
        tar[i] = (x1 - x0) * (y1 - y0);
        tlb[i] = labels[i];
    }
}

#define VT 4

__global__ __launch_bounds__(256) void matcher_main(
    const float* __restrict__ ws_ro,
    float* __restrict__ out,            // [N, T]
    int N, int T)
{
    const float* table   = ws_ro;
    const float* rowpack = (const float*)((const char*)ws_ro + ROW_OFF);
    const float* tgt     = (const float*)((const char*)ws_ro + TGT_OFF);

    const int n  = blockIdx.x;          // one row per block
    const int t0 = threadIdx.x * VT;

    // ---- block-uniform row constants -> scalar loads ----
    const float* rp = rowpack + (size_t)n * 8;
    const float x0 = rp[0], y0 = rp[1], x1 = rp[2], y1 = rp[3];
    const float px = rp[4], py = rp[5], a1 = rp[6];

    // ---- coalesced SoA target loads (one dwordx4 each) ----
    float4 TX0 = *(const float4*)(tgt + t0);
    float4 TY0 = *(const float4*)(tgt + 1024 + t0);
    float4 TX1 = *(const float4*)(tgt + 2048 + t0);
    float4 TY1 = *(const float4*)(tgt + 3072 + t0);
    float4 TAR = *(const float4*)(tgt + 4096 + t0);
    int4   LB  = *(const int4*)((const int*)(tgt + 5120) + t0);

    const float* trow = table + (size_t)n * TSTR;   // block-uniform 384B span
    float cc0 = trow[LB.x];
    float cc1 = trow[LB.y];
    float cc2 = trow[LB.z];
    float cc3 = trow[LB.w];

    float tx0a[VT] = {TX0.x, TX0.y, TX0.z, TX0.w};
    float ty0a[VT] = {TY0.x, TY0.y, TY0.z, TY0.w};
    float tx1a[VT] = {TX1.x, TX1.y, TX1.z, TX1.w};
    float ty1a[VT] = {TY1.x, TY1.y, TY1.z, TY1.w};
    float tara[VT] = {TAR.x, TAR.y, TAR.z, TAR.w};
    float cca[VT]  = {cc0, cc1, cc2, cc3};

    float4 res;
    float* resp = (float*)&res;
    #pragma unroll
    for (int j = 0; j < VT; ++j) {
        float tx0 = tx0a[j], ty0 = ty0a[j], tx1 = tx1a[j], ty1 = ty1a[j];
        float tarea = tara[j];

        // L1 on xyxy
        float l1 = fabsf(x0 - tx0) + fabsf(y0 - ty0)
                 + fabsf(x1 - tx1) + fabsf(y1 - ty1);

        // intersection / union
        float iw = fminf(x1, tx1) - fmaxf(x0, tx0);
        float ih = fminf(y1, ty1) - fmaxf(y0, ty0);
        float inter = fmaxf(iw, 0.0f) * fmaxf(ih, 0.0f);
        float uni = (a1 + tarea) - inter;

        // enclosing box (extents >= 0 since w,h >= 0)
        float cw = fmaxf(x1, tx1) - fminf(x0, tx0);
        float ch = fmaxf(y1, ty1) - fminf(y0, ty0);
        float carea = cw * ch;

        // giou with a single rcp: R = 1/(uni*carea)
        float R = __builtin_amdgcn_rcpf(uni * carea);
        float giou = (inter * carea - uni * (carea - uni)) * R;

        // inner-point: exact reference op sequence (sign-exact)
        float left = px - tx0;
        float top = py - ty0;
        float right = tx1 - px;
        float bottom = ty1 - py;
        float mind = fminf(fminf(left, top), fminf(right, bottom));

        float Cv = fmaf(5.0f, l1, fmaf(2.0f, cca[j], -2.0f * giou));
        Cv += (mind >= 0.0f) ? 0.0f : 9999.0f;
        resp[j] = Cv;
    }
    *(float4*)(out + (size_t)n * T + t0) = res;   // one coalesced store/thread
}

extern "C" void kernel_launch(void* const* d_in, const int* in_sizes, int n_in,
                              void* d_out, int out_size, void* d_ws, size_t ws_size,
                              hipStream_t stream) {
    const float* logits = (const float*)d_in[0];  // [bs,nq,nc]
    const float* boxes  = (const float*)d_in[1];  // [bs,nq,4]
    const float* points = (const float*)d_in[2];  // [bs,nq,2]
    const float* objs   = (const float*)d_in[3];  // [bs,nq,1]
    const int*   labels = (const int*)d_in[4];    // [T]
    const float* tboxes = (const float*)d_in[5];  // [T,4]
    float* out = (float*)d_out;
    float* ws = (float*)d_ws;

    int N = in_sizes[1] / 4;        // 14400
    int T = in_sizes[5] / 4;        // 1024
    int C = in_sizes[0] / N;        // 91

    prep_table<<<dim3((N * C + 255) / 256), 256, 0, stream>>>(logits, objs, ws, N, C);
    prep_packs<<<dim3((N + 255) / 256), 256, 0, stream>>>(boxes, points, labels,
                                                          tboxes, ws, N, T);
    matcher_main<<<dim3(N), 256, 0, stream>>>(ws, out, N, T);
}

// Round 11
// 99.993 us; speedup vs baseline: 1.0582x; 1.0582x over previous
//
#include <hip/hip_runtime.h>
#include <math.h>

// Hungarian matcher cost matrix:
//   C[n,t] = 5*L1(xyxy) + 2*(focal@label[t]) - 2*GIoU + 9999*inner
// N = 14400, T = 1024, C = 91. Output [N,T] f32 (59 MB).
//
// R11: PERSISTENT kernel. Ten variants (900..14400 blocks, VT 1..4, libm or
// intrinsics, LDS or not, nt or not) all pinned at ~43-48us with all pipes
// <35% busy. Two never-varied shape properties remain: (1) block
// launch/retire churn (every variant retires each block after one tile),
// (2) stores interleaved sparsely with math (~200cyc apart) instead of
// burst-issued like the 6 TB/s fill kernel. This round: grid = 1024
// resident workgroups (4/CU) grid-striding over 1800 row-tiles; per tile,
// compute ALL 8 float4 results into registers, then 8 back-to-back stores.

typedef float nfloat4 __attribute__((ext_vector_type(4)));

#define BN 8
#define BT 256
#define VT 4
#define NBLOCKS 1024

__global__ __launch_bounds__(BT) void matcher_kernel(
    const float* __restrict__ logits,   // [N, C]
    const float* __restrict__ boxes,    // [N, 4] cxcywh
    const float* __restrict__ points,   // [N, 2]
    const float* __restrict__ objs,     // [N, 1]
    const int*   __restrict__ labels,   // [T]
    const float* __restrict__ tboxes,   // [T, 4] cxcywh
    float* __restrict__ out,            // [N, T]
    int N, int C, int T)
{
    __shared__ float s_tab[96 * BN];   // TRANSPOSED: s_tab[c*8 + r]
    __shared__ float s_row[BN][8];     // x0,y0,x1,y1 | px,py,area1,po

    const int tid = threadIdx.x;
    const int t0 = tid * VT;
    const int nTiles = N / BN;         // 1800

    // ---- per-thread target constants: loaded ONCE, live in registers ----
    int4 lv = *(const int4*)(labels + t0);
    int lab[VT] = {lv.x, lv.y, lv.z, lv.w};
    float tx0[VT], ty0[VT], tx1[VT], ty1[VT], tarea[VT];
    #pragma unroll
    for (int j = 0; j < VT; ++j) {
        float4 tb = *(const float4*)(tboxes + 4 * (t0 + j));
        tx0[j] = tb.x - 0.5f * tb.z;
        ty0[j] = tb.y - 0.5f * tb.w;
        tx1[j] = tb.x + 0.5f * tb.z;
        ty1[j] = tb.y + 0.5f * tb.w;
        tarea[j] = (tx1[j] - tx0[j]) * (ty1[j] - ty0[j]);
    }

    for (int tile = blockIdx.x; tile < nTiles; tile += NBLOCKS) {
        const int rowBase = tile * BN;

        __syncthreads();   // protect LDS reuse across tiles

        // ---- Phase 1a: per-row constants ----
        if (tid < BN) {
            int n = rowBase + tid;
            float4 b = *(const float4*)(boxes + 4 * n);
            float x0 = b.x - 0.5f * b.z;
            float y0 = b.y - 0.5f * b.w;
            float x1 = b.x + 0.5f * b.z;
            float y1 = b.y + 0.5f * b.w;
            s_row[tid][0] = x0;
            s_row[tid][1] = y0;
            s_row[tid][2] = x1;
            s_row[tid][3] = y1;
            float2 p = *(const float2*)(points + 2 * n);
            s_row[tid][4] = p.x;
            s_row[tid][5] = p.y;
            s_row[tid][6] = (x1 - x0) * (y1 - y0);
            s_row[tid][7] = __builtin_amdgcn_rcpf(1.0f + __expf(-objs[n]));
        }
        __syncthreads();

        // ---- Phase 1b: focal table, transposed write s_tab[c*8+r] ----
        for (int idx = tid; idx < BN * C; idx += BT) {
            int r = idx / C;
            int c = idx - r * C;
            float lg = logits[(size_t)rowBase * C + idx];
            float ps = __builtin_amdgcn_rcpf(1.0f + __expf(-lg));
            float p = ps * s_row[r][7];
            float omp = 1.0f - p;
            float pos = 0.25f * (omp * omp) * (-__logf(p + 1e-8f));
            float neg = 0.75f * (p * p) * (-__logf(omp + 1e-8f));
            s_tab[c * BN + r] = pos - neg;
        }
        __syncthreads();

        // ---- Phase 2: compute ALL results, then burst-issue stores ----
        float cc[VT][BN];
        #pragma unroll
        for (int j = 0; j < VT; ++j) {
            const float4* tp = (const float4*)(s_tab + lab[j] * BN);
            float4 lo = tp[0];
            float4 hi = tp[1];
            cc[j][0] = lo.x; cc[j][1] = lo.y; cc[j][2] = lo.z; cc[j][3] = lo.w;
            cc[j][4] = hi.x; cc[j][5] = hi.y; cc[j][6] = hi.z; cc[j][7] = hi.w;
        }

        nfloat4 res[BN];
        #pragma unroll
        for (int r = 0; r < BN; ++r) {
            float4 ra = *(const float4*)&s_row[r][0];
            float4 rb = *(const float4*)&s_row[r][4];
            float x0 = ra.x, y0 = ra.y, x1 = ra.z, y1 = ra.w;
            float px = rb.x, py = rb.y, a1 = rb.z;

            #pragma unroll
            for (int j = 0; j < VT; ++j) {
                // L1 on xyxy
                float l1 = fabsf(x0 - tx0[j]) + fabsf(y0 - ty0[j])
                         + fabsf(x1 - tx1[j]) + fabsf(y1 - ty1[j]);

                // intersection / union
                float iw = fminf(x1, tx1[j]) - fmaxf(x0, tx0[j]);
                float ih = fminf(y1, ty1[j]) - fmaxf(y0, ty0[j]);
                float inter = fmaxf(iw, 0.0f) * fmaxf(ih, 0.0f);
                float uni = (a1 + tarea[j]) - inter;

                // enclosing box (extents >= 0 since w,h >= 0)
                float cw = fmaxf(x1, tx1[j]) - fminf(x0, tx0[j]);
                float ch = fmaxf(y1, ty1[j]) - fminf(y0, ty0[j]);
                float carea = cw * ch;

                // giou with a single rcp: R = 1/(uni*carea)
                float R = __builtin_amdgcn_rcpf(uni * carea);
                float giou = (inter * carea - uni * (carea - uni)) * R;

                // inner-point: exact reference op sequence (sign-exact)
                float left = px - tx0[j];
                float top = py - ty0[j];
                float right = tx1[j] - px;
                float bottom = ty1[j] - py;
                float mind = fminf(fminf(left, top), fminf(right, bottom));

                float Cv = fmaf(5.0f, l1, fmaf(2.0f, cc[j][r], -2.0f * giou));
                Cv += (mind >= 0.0f) ? 0.0f : 9999.0f;
                res[r][j] = Cv;
            }
        }

        // burst: 8 independent coalesced b128 stores back-to-back (MLP=8)
        float* obase = out + (size_t)rowBase * T + t0;
        #pragma unroll
        for (int r = 0; r < BN; ++r)
            *(nfloat4*)(obase + (size_t)r * T) = res[r];
    }
}

extern "C" void kernel_launch(void* const* d_in, const int* in_sizes, int n_in,
                              void* d_out, int out_size, void* d_ws, size_t ws_size,
                              hipStream_t stream) {
    const float* logits = (const float*)d_in[0];  // [bs,nq,nc]
    const float* boxes  = (const float*)d_in[1];  // [bs,nq,4]
    const float* points = (const float*)d_in[2];  // [bs,nq,2]
    const float* objs   = (const float*)d_in[3];  // [bs,nq,1]
    const int*   labels = (const int*)d_in[4];    // [T]
    const float* tboxes = (const float*)d_in[5];  // [T,4]
    float* out = (float*)d_out;

    int N = in_sizes[1] / 4;        // 14400
    int T = in_sizes[5] / 4;        // 1024
    int C = in_sizes[0] / N;        // 91

    matcher_kernel<<<dim3(NBLOCKS), BT, 0, stream>>>(logits, boxes, points, objs,
                                                     labels, tboxes, out, N, C, T);
}